// Round 5
// baseline (102.447 us; speedup 1.0000x reference)
//
#include <hip/hip_runtime.h>
#include <math.h>

#define Bsz 2048
#define Ddim 32
#define Nsz 8192
#define Kk 30
#define TPB 256
#define ROWS 4                  // rows (i) per block, in registers
#define JCH (Bsz / TPB)         // 8 chunks of 256 j's: each block sees ALL j
#define NBLK (Bsz / ROWS)       // 512 blocks = 2/CU x 256 CU
#define NW (Nsz / 32)           // 256 bitset words per row
#define CF4 (TPB * 8)           // float4 per chunk (256 rows x 8)

// R4 taught us: (a) out[] is only memset before verification, NOT between
// graph replays -> no device-side ticket possible; two dispatches are
// structural. (b) Removing a dispatch did NOT save ~10us -> main itself is
// ~33us (hiding just under the 40us top-5 cutoff), ~8x over its ~4us
// VALU/L2 floor. Theory: the old j-loop read one 128B row PER THREAD
// (lane stride 128B), so every global_load_dwordx4 touched 64 distinct
// cache lines (1 lane/line, 4x transactions, 64 tag lookups per VMEM op)
// with only 2 waves/SIMD to hide it. Fix below: stage each 32KB j-chunk
// into LDS with lane-contiguous loads (1KB/instr, 16 lines), XOR-swizzled
// (d ^= row&7 at float4 granularity; row-major 128B rows are the G4
// 32-way-conflict pattern), register-prefetch the next chunk under the
// current chunk's compute. Everything else identical to the verified R1
// kernel (77.0us): bitset mask, gram-trick dot, ROWS=4, two-dispatch tail.
__global__ __launch_bounds__(TPB, 2) void softnp_main(
    const float* __restrict__ z,
    const int*   __restrict__ pre_knn,
    const int*   __restrict__ samp,
    float*       __restrict__ wsloss,  // [NBLK] per-block loss partial
    float*       __restrict__ wscnt)   // [NBLK] per-block valid count
{
    __shared__ unsigned bits4[NW][ROWS];   // 4 KB, word-interleaved by row
    __shared__ float4   ztile[CF4];        // 32 KB swizzled j-chunk
    __shared__ float    zish[ROWS * Ddim]; // 512 B
    __shared__ int      rowsi[ROWS];
    __shared__ float    rden[4][ROWS], rnum[4][ROWS];

    const int t  = threadIdx.x;
    const int i0 = blockIdx.x * ROWS;

    // ---- stage: zero bitsets, z_i -> LDS ----
    #pragma unroll
    for (int c = 0; c < (NW * ROWS) / TPB; ++c)
        ((unsigned*)bits4)[t + c * TPB] = 0u;
    if (t < ROWS * Ddim) zish[t] = z[(size_t)i0 * Ddim + t];
    if (t < ROWS) rowsi[t] = samp[i0 + t];
    __syncthreads();

    // ---- fill bitsets: 4 rows x 30 entries ----
    if (t < ROWS * 32) {
        const int r = t >> 5, k = t & 31;
        if (k < Kk) {
            const int id = pre_knn[(size_t)rowsi[r] * Kk + k];
            atomicOr(&bits4[id >> 5][r], 1u << (id & 31));
        }
    }

    // ---- z_i rows into registers (broadcast LDS reads), |z_i|^2 ----
    float4 zi[ROWS][Ddim / 4];
    const float4* z4s = (const float4*)zish;
    #pragma unroll
    for (int r = 0; r < ROWS; ++r)
        #pragma unroll
        for (int d = 0; d < Ddim / 4; ++d)
            zi[r][d] = z4s[r * (Ddim / 4) + d];

    float si2[ROWS];
    #pragma unroll
    for (int r = 0; r < ROWS; ++r) {
        float s = 0.f;
        #pragma unroll
        for (int d = 0; d < Ddim / 4; ++d)
            s += zi[r][d].x * zi[r][d].x + zi[r][d].y * zi[r][d].y
               + zi[r][d].z * zi[r][d].z + zi[r][d].w * zi[r][d].w;
        si2[r] = s;
    }
    __syncthreads();   // bitset fill complete before main loop reads it

    // ---- swizzled-LDS addressing ----
    // Store: flat f4 idx = t + k*256 -> row = (t>>3)+k*32, d = t&7.
    //        Swizzled slot = row*8 + (d ^ (row&7)) = wbase + k*256.
    // Read:  thread t owns row t; global-d d lives at slot t*8 + (d ^ (t&7)).
    const int r8    = t >> 3;
    const int wbase = r8 * 8 + ((t & 7) ^ (r8 & 7));
    const int rbase = t * 8;
    const int rx    = t & 7;

    float den[ROWS] = {0.f, 0.f, 0.f, 0.f};
    float num[ROWS] = {0.f, 0.f, 0.f, 0.f};

    // ---- prefetch chunk 0 into registers (lane-contiguous, coalesced) ----
    const float4* zg = (const float4*)z;
    float4 stg[8];
    #pragma unroll
    for (int k = 0; k < 8; ++k) stg[k] = zg[(size_t)t + k * TPB];
    int scur = samp[t];

    #pragma unroll
    for (int c = 0; c < JCH; ++c) {
        __syncthreads();                       // prev chunk's readers done
        #pragma unroll
        for (int k = 0; k < 8; ++k) ztile[wbase + k * TPB] = stg[k];
        __syncthreads();                       // tile visible to all

        int snxt = 0;
        if (c + 1 < JCH) {                     // issue next chunk early (T14)
            #pragma unroll
            for (int k = 0; k < 8; ++k)
                stg[k] = zg[(size_t)(c + 1) * CF4 + t + k * TPB];
            snxt = samp[(c + 1) * TPB + t];
        }

        const int j = c * TPB + t;             // this thread's j-row
        float dot[ROWS] = {0.f, 0.f, 0.f, 0.f};
        float sj2 = 0.f;
        #pragma unroll
        for (int d = 0; d < 8; ++d) {
            const float4 v = ztile[rbase + (d ^ rx)];  // retrieves global-d d
            sj2 += v.x * v.x + v.y * v.y + v.z * v.z + v.w * v.w;
            #pragma unroll
            for (int r = 0; r < ROWS; ++r)
                dot[r] += zi[r][d].x * v.x + zi[r][d].y * v.y
                        + zi[r][d].z * v.z + zi[r][d].w * v.w;
        }

        const int   sj = scur;
        const uint4 bw = ((const uint4*)bits4)[sj >> 5]; // 4 rows, 1 ds_read_b128
        const unsigned bsel[4] = {bw.x, bw.y, bw.z, bw.w};
        #pragma unroll
        for (int r = 0; r < ROWS; ++r) {
            const float d2 = fmaxf(si2[r] + sj2 - 2.f * dot[r], 0.f);
            const bool diag = (j == i0 + r);
            const float e = diag ? 0.f : __expf(-sqrtf(d2));
            den[r] += e;
            if (!diag && ((bsel[r] >> (sj & 31)) & 1u)) num[r] += e;
        }

        scur = snxt;
    }

    // ---- wave shuffle reduction, 4-wave LDS combine ----
    const int lane = t & 63, wv = t >> 6;
    #pragma unroll
    for (int r = 0; r < ROWS; ++r) {
        #pragma unroll
        for (int off = 32; off > 0; off >>= 1) {
            den[r] += __shfl_xor(den[r], off, 64);
            num[r] += __shfl_xor(num[r], off, 64);
        }
    }
    if (lane == 0) {
        #pragma unroll
        for (int r = 0; r < ROWS; ++r) { rden[wv][r] = den[r]; rnum[wv][r] = num[r]; }
    }
    __syncthreads();

    // ---- per-row loss (den/num complete in-block), one pair per block ----
    if (t < ROWS) {
        float D = 0.f, Nm = 0.f;
        #pragma unroll
        for (int w = 0; w < 4; ++w) { D += rden[w][t]; Nm += rnum[w][t]; }
        float lr = 0.f, vr = 0.f;
        if (Nm > 0.f) {            // valid <=> any masked neighbor (no underflow:
            lr = -__logf(Nm / D + 1e-8f);  // exp(-d) >= e^-16 for this data)
            vr = 1.f;
        }
        // 4 active lanes: both xor steps
        lr += __shfl_xor(lr, 1, 64); vr += __shfl_xor(vr, 1, 64);
        lr += __shfl_xor(lr, 2, 64); vr += __shfl_xor(vr, 2, 64);
        if (t == 0) { wsloss[blockIdx.x] = lr; wscnt[blockIdx.x] = vr; }
    }
}

// Tiny tail: add-reduce 512 (loss, count) pairs -> out. 4 KB read, no logs.
__global__ __launch_bounds__(TPB) void softnp_final(
    const float* __restrict__ wsloss,
    const float* __restrict__ wscnt,
    float*       __restrict__ out)
{
    __shared__ float rl[4], rc[4];
    const int t = threadIdx.x;
    float L = wsloss[t] + wsloss[t + TPB];
    float C = wscnt[t]  + wscnt[t + TPB];
    #pragma unroll
    for (int off = 32; off > 0; off >>= 1) {
        L += __shfl_xor(L, off, 64);
        C += __shfl_xor(C, off, 64);
    }
    const int lane = t & 63, wv = t >> 6;
    if (lane == 0) { rl[wv] = L; rc[wv] = C; }
    __syncthreads();
    if (t == 0) {
        const float Ls = rl[0] + rl[1] + rl[2] + rl[3];
        const float Cs = rc[0] + rc[1] + rc[2] + rc[3];
        out[0] = (Cs > 0.f) ? Ls / Cs : 0.f;
    }
}

extern "C" void kernel_launch(void* const* d_in, const int* in_sizes, int n_in,
                              void* d_out, int out_size, void* d_ws, size_t ws_size,
                              hipStream_t stream)
{
    const float* z       = (const float*)d_in[0];
    const int*   pre_knn = (const int*)d_in[1];
    const int*   samp    = (const int*)d_in[2];
    float*       out     = (float*)d_out;
    float*       wsloss  = (float*)d_ws;           // [NBLK]
    float*       wscnt   = wsloss + NBLK;          // [NBLK]

    // No memset: all ws slots used are overwritten by softnp_main each launch.
    softnp_main<<<dim3(NBLK), dim3(TPB), 0, stream>>>(z, pre_knn, samp, wsloss, wscnt);
    softnp_final<<<dim3(1), dim3(TPB), 0, stream>>>(wsloss, wscnt, out);
}